// Round 20
// baseline (61.487 us; speedup 1.0000x reference)
//
#include <hip/hip_runtime.h>
#include <hip/hip_bf16.h>

#define N_CELLS  16384
#define N_SPOTS  4096
#define N_LABELS 512
#define NTHREADS 512     // build kernel block size
#define MTHREADS 256     // main kernel block size (4 waves)
#define NBUILD   8       // build blocks
#define CPB      8       // cells per block (main kernel)
#define NPAIR    (CPB/2) // packed-f32 cell pairs
#define TABLE    6144    // padded spot-table capacity (float2)
#define SCHED    2048    // meta offset of the wave schedule (36 ints)

typedef float v2f __attribute__((ext_vector_type(2)));
typedef float v4f __attribute__((ext_vector_type(4)));   // NT-store-compatible

// Native exp2 (single v_exp_f32).
__device__ __forceinline__ float fast_exp2(float x) {
    float r;
    asm("v_exp_f32 %0, %1" : "=v"(r) : "v"(x));
    return r;
}

// log2(e)/2 : fold both 1/(2D) and log2(e) into the coordinate prescale
#define HALF_LOG2E 0.72134752044448170f

// ---------------------------------------------------------------------------
// Build — R8 byte-identical (wide, 8 blocks; scatter-emit), PLUS an appended
// deterministic 4-bin wave schedule (thread 0 of block 0):
//   - LPT chunks 1..7 into bins 0..2 (each <=3 segments)
//   - chunk 0 split 2-way: first share [0,x) to empty bin 3 (base carrier),
//     remainder [x,m0) to the lightest bin  ->  bin loads ~{21,21,19,21}
//     instead of pairing's {30,17,17,17}.
// sched layout: meta[SCHED + (bin*3 + seg)*3 + {0:chunk,1:k0,2:k1}], chunk=-1
// sentinel for empty slots.
// ---------------------------------------------------------------------------
__global__ __launch_bounds__(512) void build_kernel(
    const float* __restrict__ ex, const float* __restrict__ ey,
    const int* __restrict__ labels, const float* __restrict__ dconst,
    float2* __restrict__ table, int* __restrict__ meta)
{
    __shared__ unsigned short s_lab[N_SPOTS];   // 8 KB
    __shared__ int s_h[NBUILD][N_LABELS];       // 16 KB per-chunk histograms
    __shared__ int s_c[N_LABELS];               // total counts
    __shared__ int s_h2[128];                   // histogram of counts
    __shared__ int s_suf[128];                  // suffix sums of h2
    __shared__ int s_pcw[32 * 8];               // per-(count,wave) label counts
    __shared__ int s_rlab[N_LABELS];            // rank -> label
    __shared__ int s_rcnt[N_LABELS];            // rank -> count
    __shared__ int s_wmax[8];
    __shared__ int s_wbase[8];
    __shared__ int s_slot[N_LABELS];            // label -> first table slot
    __shared__ int s_kcur[N_LABELS];            // label -> next ordinal (this block)

    const int t = threadIdx.x;
    const int lane = t & 63, w = t >> 6;
    const int b = blockIdx.x;

    #pragma unroll
    for (int q = 0; q < NBUILD; ++q) s_h[q][t] = 0;
    if (t < 128) s_h2[t] = 0;
    for (int i = t; i < N_SPOTS; i += NTHREADS) s_lab[i] = (unsigned short)labels[i];
    __syncthreads();

    // per-chunk histograms (chunk = spot index >> 9)
    for (int i = t; i < N_SPOTS; i += NTHREADS) atomicAdd(&s_h[i >> 9][s_lab[i]], 1);
    __syncthreads();

    // total count + my block's prefix for label t
    int myc = 0, pre = 0;
    #pragma unroll
    for (int q = 0; q < NBUILD; ++q) {
        if (q == b) pre = myc;
        myc += s_h[q][t];
    }
    s_c[t] = myc;
    const int mycc = myc < 127 ? myc : 127;
    atomicAdd(&s_h2[mycc], 1);
    __syncthreads();

    // suffix-scan h2: s_suf[v] = #labels with count >= v
    if (t < 128) s_suf[t] = s_h2[t];
    __syncthreads();
    for (int off = 1; off < 128; off <<= 1) {
        int add = (t < 128 && t + off < 128) ? s_suf[t + off] : 0;
        __syncthreads();
        if (t < 128) s_suf[t] += add;
        __syncthreads();
    }

    // position among equal-count labels (label id asc), ballot-based
    int pos_w = 0;
    for (int v = 0; v < 32; ++v) {
        unsigned long long mask = __ballot(myc == v);
        if (myc == v) pos_w = __popcll(mask & ((1ull << lane) - 1ull));
        if (lane == 0) s_pcw[v * 8 + w] = __popcll(mask);
    }
    __syncthreads();
    int pos;
    if (myc < 32) {
        pos = pos_w;
        for (int w2 = 0; w2 < w; ++w2) pos += s_pcw[myc * 8 + w2];
    } else {  // astronomically rare for Poisson(8); deterministic fallback
        pos = 0;
        for (int j = 0; j < t; ++j) pos += (s_c[j] == myc) ? 1 : 0;
    }
    const int r = ((myc < 127) ? s_suf[myc + 1] : 0) + pos;   // rank of label t
    s_rlab[r] = t;
    s_rcnt[r] = myc;
    __syncthreads();

    // per-wave max count over rank space (thread t ~ rank t)
    int v = s_rcnt[t];
    #pragma unroll
    for (int off = 32; off; off >>= 1) { int o = __shfl_xor(v, off); v = v > o ? v : o; }
    if (lane == 0) s_wmax[w] = v;
    __syncthreads();
    if (t == 0) {
        int pb = 0;
        #pragma unroll
        for (int w2 = 0; w2 < 8; ++w2) { s_wbase[w2] = 64 * pb; pb += s_wmax[w2]; }
    }
    __syncthreads();

    // label t: slot base from its rank r; cursor starts at my block's prefix
    s_slot[t] = s_wbase[r >> 6] + (r & 63);
    s_kcur[t] = pre;
    __syncthreads();

    const float Dv = dconst[0];
    const float sc = sqrtf(HALF_LOG2E / Dv);  // dx'^2+dy'^2 = d2*log2e/(2D)

    // emit my block's 512-spot slice (coalesced ex/ey reads)
    {
        const int i = b * NTHREADS + t;
        const int l = s_lab[i];
        const int k = atomicAdd(&s_kcur[l], 1);
        table[s_slot[l] + k * 64] = make_float2(ex[i] * sc, ey[i] * sc);
    }

    // fill pad slots of ranks [64b, 64b+64): rank q = b*64 + lane,
    // sub-iterator t>>6 strides the k-range by 8
    {
        const int q    = b * 64 + lane;
        const int trip = s_wmax[b];
        const int base = s_wbase[b];
        for (int k = s_rcnt[q] + (t >> 6); k < trip; k += 8)
            table[base + k * 64 + lane] = make_float2(1e8f, 0.0f);
    }

    if (b == 0) {
        meta[t]                = s_wbase[t >> 6];
        meta[NTHREADS + t]     = s_wmax[t >> 6];
        meta[2 * NTHREADS + t] = s_rlab[t];
        meta[3 * NTHREADS + t] = s_rcnt[t];
    }

    // ---- appended: deterministic balanced wave schedule (block 0, t 0) ----
    if (b == 0 && t == 0) {
        int load[4] = {0, 0, 0, 0};
        int nseg[4] = {0, 0, 0, 0};
        for (int i = 0; i < 36; ++i) meta[SCHED + i] = -1;
        // LPT chunks 1..7 into bins 0..2
        for (int c = 1; c < 8; ++c) {
            int bm = 0;
            for (int q = 1; q < 3; ++q) if (load[q] < load[bm]) bm = q;
            int s = nseg[bm]++;
            meta[SCHED + (bm * 3 + s) * 3 + 0] = c;
            meta[SCHED + (bm * 3 + s) * 3 + 1] = 0;
            meta[SCHED + (bm * 3 + s) * 3 + 2] = s_wmax[c];
            load[bm] += s_wmax[c];
        }
        // split chunk 0: [0,x) -> bin 3 (carrier), [x,m0) -> lightest bin
        const int m0 = s_wmax[0];
        int bm = -1;
        for (int q = 0; q < 3; ++q)
            if (nseg[q] < 3 && (bm < 0 || load[q] < load[bm])) bm = q;
        int x = (load[bm] + m0 + 1) / 2;
        if (x > m0) x = m0;
        if (x < 1)  x = 1;
        meta[SCHED + (3 * 3 + 0) * 3 + 0] = 0;
        meta[SCHED + (3 * 3 + 0) * 3 + 1] = 0;
        meta[SCHED + (3 * 3 + 0) * 3 + 2] = x;
        if (x < m0 && bm >= 0) {
            int s = nseg[bm]++;
            meta[SCHED + (bm * 3 + s) * 3 + 0] = 0;
            meta[SCHED + (bm * 3 + s) * 3 + 1] = x;
            meta[SCHED + (bm * 3 + s) * 3 + 2] = m0;
        }
    }
}

// ---------------------------------------------------------------------------
// One segment of the K-loop: accumulate into acc[] over [0, trip) slots.
// ---------------------------------------------------------------------------
__device__ __forceinline__ void kphase(
    const v2f* __restrict__ seg, int trip,
    const v2f* zxn, const v2f* zyn, v2f* acc)
{
    if (trip <= 0) return;
    v2f xy = seg[0];
    for (int p = 0; p < trip; ++p) {
        const int pn = (p + 1 < trip) ? p + 1 : p;   // scalar select
        v2f nxt = seg[(size_t)pn * 64];              // depth-1 prefetch
        const v2f xx = (v2f){xy.x, xy.x};
        const v2f yy = (v2f){xy.y, xy.y};
        #pragma unroll
        for (int j = 0; j < NPAIR; ++j) {
            v2f dx  = xx + zxn[j];                              // v_pk_add
            v2f dy  = yy + zyn[j];                              // v_pk_add
            v2f m   = dy * dy;                                  // v_pk_mul
            v2f nd2 = __builtin_elementwise_fma(-dx, dx, -m);   // v_pk_fma
            v2f e   = (v2f){ fast_exp2(nd2.x), fast_exp2(nd2.y) };
            acc[j] += e;                                        // v_pk_add
        }
        xy = nxt;
    }
}

// ---------------------------------------------------------------------------
// Main — R14 grid (2048 x 256 threads, 8 cells/block) but waves execute the
// build-computed balanced schedule (<=3 segments/bin, chunk 0 split 2-way).
// Partial results combine via ds_add_f32 into zero-init tr; the k0==0 share
// carries the UNDERFLOW_NU base. <=2 contributors per tr entry, and 2-input
// fp add is commutative -> bitwise-deterministic output.
// ---------------------------------------------------------------------------
__global__ __launch_bounds__(MTHREADS) void diffusion_main_kernel(
    const float* __restrict__ z, const float* __restrict__ dconst,
    const v2f* __restrict__ table, const int* __restrict__ meta,
    float* __restrict__ out)
{
    __shared__ float tr[CPB * N_LABELS];   // 16 KB transpose/accumulate buffer

    const int t = threadIdx.x;
    const int lane = t & 63, w = t >> 6;   // 4 waves
    const int bid = blockIdx.x;

    // zero the accumulate buffer
    #pragma unroll
    for (int m = 0; m < CPB * N_LABELS / MTHREADS; ++m)   // 16 stores
        tr[t + m * MTHREADS] = 0.0f;

    const float D    = dconst[0];
    const float sc   = sqrtf(HALF_LOG2E / D);
    const float norm = 1.0f / (6.28318530717958647f * D);

    const int cell0 = bid * CPB;
    v2f zxn[NPAIR], zyn[NPAIR];
    #pragma unroll
    for (int j = 0; j < NPAIR; ++j) {
        zxn[j] = (v2f){ -z[2 * (cell0 + 2 * j)]     * sc,
                        -z[2 * (cell0 + 2 * j + 1)] * sc };
        zyn[j] = (v2f){ -z[2 * (cell0 + 2 * j) + 1]     * sc,
                        -z[2 * (cell0 + 2 * j + 1) + 1] * sc };
    }
    __syncthreads();   // tr zeroed before any atomic adds

    const int bin = (w + bid) & 3;   // rotate bins across SIMDs by block

    #pragma unroll
    for (int s = 0; s < 3; ++s) {
        const int c = __builtin_amdgcn_readfirstlane(
                          meta[SCHED + (bin * 3 + s) * 3 + 0]);
        if (c >= 0) {
            const int k0 = __builtin_amdgcn_readfirstlane(
                               meta[SCHED + (bin * 3 + s) * 3 + 1]);
            const int k1 = __builtin_amdgcn_readfirstlane(
                               meta[SCHED + (bin * 3 + s) * 3 + 2]);
            const int u     = c * 64 + lane;
            const int wbase = __builtin_amdgcn_readfirstlane(meta[u]);
            const int lab   = meta[2 * NTHREADS + u];
            const float cnt = (float)meta[3 * NTHREADS + u];

            v2f acc[NPAIR];
            #pragma unroll
            for (int j = 0; j < NPAIR; ++j) acc[j] = (v2f){0.f, 0.f};

            kphase(table + wbase + lane + (size_t)k0 * 64, k1 - k0,
                   zxn, zyn, acc);

            const float base = (k0 == 0) ? cnt * 1e-12f : 0.0f;  // carrier
            #pragma unroll
            for (int j = 0; j < NPAIR; ++j) {
                unsafeAtomicAdd(&tr[(2 * j)     * N_LABELS + lab],
                                fmaf(acc[j].x, norm, base));
                unsafeAtomicAdd(&tr[(2 * j + 1) * N_LABELS + lab],
                                fmaf(acc[j].y, norm, base));
            }
        }
    }
    __syncthreads();

    const v4f* tr4 = (const v4f*)tr;
    v4f* out4 = (v4f*)(out + (size_t)cell0 * N_LABELS);
    #pragma unroll
    for (int rr = 0; rr < CPB * N_LABELS / 4 / MTHREADS; ++rr)   // 4 iters
        __builtin_nontemporal_store(tr4[t + rr * MTHREADS],
                                    &out4[t + rr * MTHREADS]);
}

// ---------------------------------------------------------------------------
extern "C" void kernel_launch(void* const* d_in, const int* in_sizes, int n_in,
                              void* d_out, int out_size, void* d_ws, size_t ws_size,
                              hipStream_t stream)
{
    const float* z      = (const float*)d_in[0];  // (16384, 2)
    const float* dconst = (const float*)d_in[1];  // scalar
    const float* ex     = (const float*)d_in[2];  // (4096,)
    const float* ey     = (const float*)d_in[3];  // (4096,)
    const int*   labels = (const int*)d_in[4];    // (4096,)
    float*       out    = (float*)d_out;          // (16384, 512)

    float2* table = (float2*)d_ws;                                        // 48 KB
    int*    meta  = (int*)((char*)d_ws + (size_t)TABLE * sizeof(float2)); // 8.2 KB

    build_kernel<<<NBUILD, NTHREADS, 0, stream>>>(ex, ey, labels, dconst, table, meta);

    diffusion_main_kernel<<<N_CELLS / CPB, MTHREADS, 0, stream>>>(
        z, dconst, (const v2f*)table, meta, out);
}

// Round 21
// 31.434 us; speedup vs baseline: 1.9561x; 1.9561x over previous
//
#include <hip/hip_runtime.h>
#include <hip/hip_bf16.h>

#define N_CELLS  16384
#define N_SPOTS  4096
#define N_LABELS 512
#define NTHREADS 512     // build kernel block size
#define MTHREADS 256     // main kernel block size (4 waves)
#define NBUILD   8       // build blocks
#define CPB      8       // cells per block (main kernel)
#define NPAIR    (CPB/2) // packed-f32 cell pairs
#define TABLE    6144    // padded spot-table capacity (float2)
#define SCHED    2048    // meta offset of the wave schedule (36 ints)

typedef float v2f __attribute__((ext_vector_type(2)));
typedef float v4f __attribute__((ext_vector_type(4)));   // NT-store-compatible

// Native exp2 (single v_exp_f32).
__device__ __forceinline__ float fast_exp2(float x) {
    float r;
    asm("v_exp_f32 %0, %1" : "=v"(r) : "v"(x));
    return r;
}

// log2(e)/2 : fold both 1/(2D) and log2(e) into the coordinate prescale
#define HALF_LOG2E 0.72134752044448170f

// ---------------------------------------------------------------------------
// Build — byte-identical to round 20 (R8 core + appended 4-bin schedule).
// ---------------------------------------------------------------------------
__global__ __launch_bounds__(512) void build_kernel(
    const float* __restrict__ ex, const float* __restrict__ ey,
    const int* __restrict__ labels, const float* __restrict__ dconst,
    float2* __restrict__ table, int* __restrict__ meta)
{
    __shared__ unsigned short s_lab[N_SPOTS];   // 8 KB
    __shared__ int s_h[NBUILD][N_LABELS];       // 16 KB per-chunk histograms
    __shared__ int s_c[N_LABELS];               // total counts
    __shared__ int s_h2[128];                   // histogram of counts
    __shared__ int s_suf[128];                  // suffix sums of h2
    __shared__ int s_pcw[32 * 8];               // per-(count,wave) label counts
    __shared__ int s_rlab[N_LABELS];            // rank -> label
    __shared__ int s_rcnt[N_LABELS];            // rank -> count
    __shared__ int s_wmax[8];
    __shared__ int s_wbase[8];
    __shared__ int s_slot[N_LABELS];            // label -> first table slot
    __shared__ int s_kcur[N_LABELS];            // label -> next ordinal (this block)

    const int t = threadIdx.x;
    const int lane = t & 63, w = t >> 6;
    const int b = blockIdx.x;

    #pragma unroll
    for (int q = 0; q < NBUILD; ++q) s_h[q][t] = 0;
    if (t < 128) s_h2[t] = 0;
    for (int i = t; i < N_SPOTS; i += NTHREADS) s_lab[i] = (unsigned short)labels[i];
    __syncthreads();

    // per-chunk histograms (chunk = spot index >> 9)
    for (int i = t; i < N_SPOTS; i += NTHREADS) atomicAdd(&s_h[i >> 9][s_lab[i]], 1);
    __syncthreads();

    // total count + my block's prefix for label t
    int myc = 0, pre = 0;
    #pragma unroll
    for (int q = 0; q < NBUILD; ++q) {
        if (q == b) pre = myc;
        myc += s_h[q][t];
    }
    s_c[t] = myc;
    const int mycc = myc < 127 ? myc : 127;
    atomicAdd(&s_h2[mycc], 1);
    __syncthreads();

    // suffix-scan h2: s_suf[v] = #labels with count >= v
    if (t < 128) s_suf[t] = s_h2[t];
    __syncthreads();
    for (int off = 1; off < 128; off <<= 1) {
        int add = (t < 128 && t + off < 128) ? s_suf[t + off] : 0;
        __syncthreads();
        if (t < 128) s_suf[t] += add;
        __syncthreads();
    }

    // position among equal-count labels (label id asc), ballot-based
    int pos_w = 0;
    for (int v = 0; v < 32; ++v) {
        unsigned long long mask = __ballot(myc == v);
        if (myc == v) pos_w = __popcll(mask & ((1ull << lane) - 1ull));
        if (lane == 0) s_pcw[v * 8 + w] = __popcll(mask);
    }
    __syncthreads();
    int pos;
    if (myc < 32) {
        pos = pos_w;
        for (int w2 = 0; w2 < w; ++w2) pos += s_pcw[myc * 8 + w2];
    } else {  // astronomically rare for Poisson(8); deterministic fallback
        pos = 0;
        for (int j = 0; j < t; ++j) pos += (s_c[j] == myc) ? 1 : 0;
    }
    const int r = ((myc < 127) ? s_suf[myc + 1] : 0) + pos;   // rank of label t
    s_rlab[r] = t;
    s_rcnt[r] = myc;
    __syncthreads();

    // per-wave max count over rank space (thread t ~ rank t)
    int v = s_rcnt[t];
    #pragma unroll
    for (int off = 32; off; off >>= 1) { int o = __shfl_xor(v, off); v = v > o ? v : o; }
    if (lane == 0) s_wmax[w] = v;
    __syncthreads();
    if (t == 0) {
        int pb = 0;
        #pragma unroll
        for (int w2 = 0; w2 < 8; ++w2) { s_wbase[w2] = 64 * pb; pb += s_wmax[w2]; }
    }
    __syncthreads();

    // label t: slot base from its rank r; cursor starts at my block's prefix
    s_slot[t] = s_wbase[r >> 6] + (r & 63);
    s_kcur[t] = pre;
    __syncthreads();

    const float Dv = dconst[0];
    const float sc = sqrtf(HALF_LOG2E / Dv);  // dx'^2+dy'^2 = d2*log2e/(2D)

    // emit my block's 512-spot slice (coalesced ex/ey reads)
    {
        const int i = b * NTHREADS + t;
        const int l = s_lab[i];
        const int k = atomicAdd(&s_kcur[l], 1);
        table[s_slot[l] + k * 64] = make_float2(ex[i] * sc, ey[i] * sc);
    }

    // fill pad slots of ranks [64b, 64b+64): rank q = b*64 + lane,
    // sub-iterator t>>6 strides the k-range by 8
    {
        const int q    = b * 64 + lane;
        const int trip = s_wmax[b];
        const int base = s_wbase[b];
        for (int k = s_rcnt[q] + (t >> 6); k < trip; k += 8)
            table[base + k * 64 + lane] = make_float2(1e8f, 0.0f);
    }

    if (b == 0) {
        meta[t]                = s_wbase[t >> 6];
        meta[NTHREADS + t]     = s_wmax[t >> 6];
        meta[2 * NTHREADS + t] = s_rlab[t];
        meta[3 * NTHREADS + t] = s_rcnt[t];
    }

    // ---- appended: deterministic balanced wave schedule (block 0, t 0) ----
    if (b == 0 && t == 0) {
        int load[4] = {0, 0, 0, 0};
        int nseg[4] = {0, 0, 0, 0};
        for (int i = 0; i < 36; ++i) meta[SCHED + i] = -1;
        // LPT chunks 1..7 into bins 0..2
        for (int c = 1; c < 8; ++c) {
            int bm = 0;
            for (int q = 1; q < 3; ++q) if (load[q] < load[bm]) bm = q;
            int s = nseg[bm]++;
            meta[SCHED + (bm * 3 + s) * 3 + 0] = c;
            meta[SCHED + (bm * 3 + s) * 3 + 1] = 0;
            meta[SCHED + (bm * 3 + s) * 3 + 2] = s_wmax[c];
            load[bm] += s_wmax[c];
        }
        // split chunk 0: [0,x) -> bin 3 (carrier), [x,m0) -> lightest bin
        const int m0 = s_wmax[0];
        int bm = -1;
        for (int q = 0; q < 3; ++q)
            if (nseg[q] < 3 && (bm < 0 || load[q] < load[bm])) bm = q;
        int x = (load[bm] + m0 + 1) / 2;
        if (x > m0) x = m0;
        if (x < 1)  x = 1;
        meta[SCHED + (3 * 3 + 0) * 3 + 0] = 0;
        meta[SCHED + (3 * 3 + 0) * 3 + 1] = 0;
        meta[SCHED + (3 * 3 + 0) * 3 + 2] = x;
        if (x < m0 && bm >= 0) {
            int s = nseg[bm]++;
            meta[SCHED + (bm * 3 + s) * 3 + 0] = 0;
            meta[SCHED + (bm * 3 + s) * 3 + 1] = x;
            meta[SCHED + (bm * 3 + s) * 3 + 2] = m0;
        }
    }
}

// ---------------------------------------------------------------------------
// One segment of the K-loop: accumulate into acc[] over [0, trip) slots.
// ---------------------------------------------------------------------------
__device__ __forceinline__ void kphase(
    const v2f* __restrict__ seg, int trip,
    const v2f* zxn, const v2f* zyn, v2f* acc)
{
    if (trip <= 0) return;
    v2f xy = seg[0];
    for (int p = 0; p < trip; ++p) {
        const int pn = (p + 1 < trip) ? p + 1 : p;   // scalar select
        v2f nxt = seg[(size_t)pn * 64];              // depth-1 prefetch
        const v2f xx = (v2f){xy.x, xy.x};
        const v2f yy = (v2f){xy.y, xy.y};
        #pragma unroll
        for (int j = 0; j < NPAIR; ++j) {
            v2f dx  = xx + zxn[j];                              // v_pk_add
            v2f dy  = yy + zyn[j];                              // v_pk_add
            v2f m   = dy * dy;                                  // v_pk_mul
            v2f nd2 = __builtin_elementwise_fma(-dx, dx, -m);   // v_pk_fma
            v2f e   = (v2f){ fast_exp2(nd2.x), fast_exp2(nd2.y) };
            acc[j] += e;                                        // v_pk_add
        }
        xy = nxt;
    }
}

// ---------------------------------------------------------------------------
// Main — balanced 4-bin schedule, NO ATOMICS (R20's scattered ds_add_f32
// measured ~54us of serialization — R6's lesson). Every chunk has exactly
// one owning wave -> plain single-writer stores into tr. The only 2-writer
// case (split chunk 0) keeps its partial in REGISTERS, and after the block
// barrier does a plain read-modify-write (single writer then; fixed order ->
// bitwise deterministic).
// ---------------------------------------------------------------------------
__global__ __launch_bounds__(MTHREADS) void diffusion_main_kernel(
    const float* __restrict__ z, const float* __restrict__ dconst,
    const v2f* __restrict__ table, const int* __restrict__ meta,
    float* __restrict__ out)
{
    __shared__ float tr[CPB * N_LABELS];   // 16 KB transpose buffer

    const int t = threadIdx.x;
    const int lane = t & 63, w = t >> 6;   // 4 waves
    const int bid = blockIdx.x;

    const float D    = dconst[0];
    const float sc   = sqrtf(HALF_LOG2E / D);
    const float norm = 1.0f / (6.28318530717958647f * D);

    const int cell0 = bid * CPB;
    v2f zxn[NPAIR], zyn[NPAIR];
    #pragma unroll
    for (int j = 0; j < NPAIR; ++j) {
        zxn[j] = (v2f){ -z[2 * (cell0 + 2 * j)]     * sc,
                        -z[2 * (cell0 + 2 * j + 1)] * sc };
        zyn[j] = (v2f){ -z[2 * (cell0 + 2 * j) + 1]     * sc,
                        -z[2 * (cell0 + 2 * j + 1) + 1] * sc };
    }

    const int bin = (w + bid) & 3;   // rotate bins across SIMDs by block

    v2f accS[NPAIR];                 // deferred split-share partial (registers)
    #pragma unroll
    for (int j = 0; j < NPAIR; ++j) accS[j] = (v2f){0.f, 0.f};
    bool haveSplit = false;
    int  labS = 0;

    #pragma unroll
    for (int s = 0; s < 3; ++s) {
        const int c = __builtin_amdgcn_readfirstlane(
                          meta[SCHED + (bin * 3 + s) * 3 + 0]);
        if (c >= 0) {
            const int k0 = __builtin_amdgcn_readfirstlane(
                               meta[SCHED + (bin * 3 + s) * 3 + 1]);
            const int k1 = __builtin_amdgcn_readfirstlane(
                               meta[SCHED + (bin * 3 + s) * 3 + 2]);
            const int u     = c * 64 + lane;
            const int wbase = __builtin_amdgcn_readfirstlane(meta[u]);
            const int lab   = meta[2 * NTHREADS + u];
            const float cnt = (float)meta[3 * NTHREADS + u];

            v2f acc[NPAIR];
            #pragma unroll
            for (int j = 0; j < NPAIR; ++j) acc[j] = (v2f){0.f, 0.f};

            kphase(table + wbase + lane + (size_t)k0 * 64, k1 - k0,
                   zxn, zyn, acc);

            if (c == 0 && k0 > 0) {
                // second share of split chunk 0: defer to post-barrier RMW
                #pragma unroll
                for (int j = 0; j < NPAIR; ++j) accS[j] = acc[j];
                haveSplit = true;
                labS = lab;
            } else {
                const float base = cnt * 1e-12f;   // hoisted UNDERFLOW_NU
                #pragma unroll
                for (int j = 0; j < NPAIR; ++j) {
                    tr[(2 * j)     * N_LABELS + lab] = fmaf(acc[j].x, norm, base);
                    tr[(2 * j + 1) * N_LABELS + lab] = fmaf(acc[j].y, norm, base);
                }
            }
        }
    }
    __syncthreads();          // all single-writer stores complete

    if (haveSplit) {          // wave-uniform branch; single writer per entry
        #pragma unroll
        for (int j = 0; j < NPAIR; ++j) {
            tr[(2 * j)     * N_LABELS + labS] += accS[j].x * norm;
            tr[(2 * j + 1) * N_LABELS + labS] += accS[j].y * norm;
        }
    }
    __syncthreads();

    const v4f* tr4 = (const v4f*)tr;
    v4f* out4 = (v4f*)(out + (size_t)cell0 * N_LABELS);
    #pragma unroll
    for (int rr = 0; rr < CPB * N_LABELS / 4 / MTHREADS; ++rr)   // 4 iters
        __builtin_nontemporal_store(tr4[t + rr * MTHREADS],
                                    &out4[t + rr * MTHREADS]);
}

// ---------------------------------------------------------------------------
extern "C" void kernel_launch(void* const* d_in, const int* in_sizes, int n_in,
                              void* d_out, int out_size, void* d_ws, size_t ws_size,
                              hipStream_t stream)
{
    const float* z      = (const float*)d_in[0];  // (16384, 2)
    const float* dconst = (const float*)d_in[1];  // scalar
    const float* ex     = (const float*)d_in[2];  // (4096,)
    const float* ey     = (const float*)d_in[3];  // (4096,)
    const int*   labels = (const int*)d_in[4];    // (4096,)
    float*       out    = (float*)d_out;          // (16384, 512)

    float2* table = (float2*)d_ws;                                        // 48 KB
    int*    meta  = (int*)((char*)d_ws + (size_t)TABLE * sizeof(float2)); // 8.2 KB

    build_kernel<<<NBUILD, NTHREADS, 0, stream>>>(ex, ey, labels, dconst, table, meta);

    diffusion_main_kernel<<<N_CELLS / CPB, MTHREADS, 0, stream>>>(
        z, dconst, (const v2f*)table, meta, out);
}

// Round 22
// 29.191 us; speedup vs baseline: 2.1064x; 1.0768x over previous
//
#include <hip/hip_runtime.h>
#include <hip/hip_bf16.h>

#define N_CELLS  16384
#define N_SPOTS  4096
#define N_LABELS 512
#define NTHREADS 512     // build kernel block size
#define MTHREADS 256     // main kernel block size (4 waves, 8 blocks/CU)
#define NBUILD   8       // build blocks
#define CPB      8       // cells per block (main kernel)
#define NPAIR    (CPB/2) // packed-f32 cell pairs
#define TABLE    6144    // padded spot-table capacity (float2)

typedef float v2f __attribute__((ext_vector_type(2)));
typedef float v4f __attribute__((ext_vector_type(4)));   // NT-store-compatible

// Native exp2 (single v_exp_f32).
__device__ __forceinline__ float fast_exp2(float x) {
    float r;
    asm("v_exp_f32 %0, %1" : "=v"(r) : "v"(x));
    return r;
}

// log2(e)/2 : fold both 1/(2D) and log2(e) into the coordinate prescale
#define HALF_LOG2E 0.72134752044448170f

// ---------------------------------------------------------------------------
// Build — byte-identical to rounds 8-14 (wide, 8 blocks; scatter-emit).
// ---------------------------------------------------------------------------
__global__ __launch_bounds__(512) void build_kernel(
    const float* __restrict__ ex, const float* __restrict__ ey,
    const int* __restrict__ labels, const float* __restrict__ dconst,
    float2* __restrict__ table, int* __restrict__ meta)
{
    __shared__ unsigned short s_lab[N_SPOTS];   // 8 KB
    __shared__ int s_h[NBUILD][N_LABELS];       // 16 KB per-chunk histograms
    __shared__ int s_c[N_LABELS];               // total counts
    __shared__ int s_h2[128];                   // histogram of counts
    __shared__ int s_suf[128];                  // suffix sums of h2
    __shared__ int s_pcw[32 * 8];               // per-(count,wave) label counts
    __shared__ int s_rlab[N_LABELS];            // rank -> label
    __shared__ int s_rcnt[N_LABELS];            // rank -> count
    __shared__ int s_wmax[8];
    __shared__ int s_wbase[8];
    __shared__ int s_slot[N_LABELS];            // label -> first table slot
    __shared__ int s_kcur[N_LABELS];            // label -> next ordinal (this block)

    const int t = threadIdx.x;
    const int lane = t & 63, w = t >> 6;
    const int b = blockIdx.x;

    #pragma unroll
    for (int q = 0; q < NBUILD; ++q) s_h[q][t] = 0;
    if (t < 128) s_h2[t] = 0;
    for (int i = t; i < N_SPOTS; i += NTHREADS) s_lab[i] = (unsigned short)labels[i];
    __syncthreads();

    // per-chunk histograms (chunk = spot index >> 9)
    for (int i = t; i < N_SPOTS; i += NTHREADS) atomicAdd(&s_h[i >> 9][s_lab[i]], 1);
    __syncthreads();

    // total count + my block's prefix for label t
    int myc = 0, pre = 0;
    #pragma unroll
    for (int q = 0; q < NBUILD; ++q) {
        if (q == b) pre = myc;
        myc += s_h[q][t];
    }
    s_c[t] = myc;
    const int mycc = myc < 127 ? myc : 127;
    atomicAdd(&s_h2[mycc], 1);
    __syncthreads();

    // suffix-scan h2: s_suf[v] = #labels with count >= v
    if (t < 128) s_suf[t] = s_h2[t];
    __syncthreads();
    for (int off = 1; off < 128; off <<= 1) {
        int add = (t < 128 && t + off < 128) ? s_suf[t + off] : 0;
        __syncthreads();
        if (t < 128) s_suf[t] += add;
        __syncthreads();
    }

    // position among equal-count labels (label id asc), ballot-based
    int pos_w = 0;
    for (int v = 0; v < 32; ++v) {
        unsigned long long mask = __ballot(myc == v);
        if (myc == v) pos_w = __popcll(mask & ((1ull << lane) - 1ull));
        if (lane == 0) s_pcw[v * 8 + w] = __popcll(mask);
    }
    __syncthreads();
    int pos;
    if (myc < 32) {
        pos = pos_w;
        for (int w2 = 0; w2 < w; ++w2) pos += s_pcw[myc * 8 + w2];
    } else {  // astronomically rare for Poisson(8); deterministic fallback
        pos = 0;
        for (int j = 0; j < t; ++j) pos += (s_c[j] == myc) ? 1 : 0;
    }
    const int r = ((myc < 127) ? s_suf[myc + 1] : 0) + pos;   // rank of label t
    s_rlab[r] = t;
    s_rcnt[r] = myc;
    __syncthreads();

    // per-wave max count over rank space (thread t ~ rank t)
    int v = s_rcnt[t];
    #pragma unroll
    for (int off = 32; off; off >>= 1) { int o = __shfl_xor(v, off); v = v > o ? v : o; }
    if (lane == 0) s_wmax[w] = v;
    __syncthreads();
    if (t == 0) {
        int pb = 0;
        #pragma unroll
        for (int w2 = 0; w2 < 8; ++w2) { s_wbase[w2] = 64 * pb; pb += s_wmax[w2]; }
    }
    __syncthreads();

    // label t: slot base from its rank r; cursor starts at my block's prefix
    s_slot[t] = s_wbase[r >> 6] + (r & 63);
    s_kcur[t] = pre;
    __syncthreads();

    const float Dv = dconst[0];
    const float sc = sqrtf(HALF_LOG2E / Dv);  // dx'^2+dy'^2 = d2*log2e/(2D)

    // emit my block's 512-spot slice (coalesced ex/ey reads)
    {
        const int i = b * NTHREADS + t;
        const int l = s_lab[i];
        const int k = atomicAdd(&s_kcur[l], 1);
        table[s_slot[l] + k * 64] = make_float2(ex[i] * sc, ey[i] * sc);
    }

    // fill pad slots of ranks [64b, 64b+64): rank q = b*64 + lane,
    // sub-iterator t>>6 strides the k-range by 8
    {
        const int q    = b * 64 + lane;
        const int trip = s_wmax[b];
        const int base = s_wbase[b];
        for (int k = s_rcnt[q] + (t >> 6); k < trip; k += 8)
            table[base + k * 64 + lane] = make_float2(1e8f, 0.0f);
    }

    if (b == 0) {
        meta[t]                = s_wbase[t >> 6];
        meta[NTHREADS + t]     = s_wmax[t >> 6];
        meta[2 * NTHREADS + t] = s_rlab[t];
        meta[3 * NTHREADS + t] = s_rcnt[t];
    }
}

// ---------------------------------------------------------------------------
// One chunk-phase of the K-loop: accumulate into acc[] over trip slots.
// ---------------------------------------------------------------------------
__device__ __forceinline__ void kphase(
    const v2f* __restrict__ seg, int trip,
    const v2f* zxn, const v2f* zyn, v2f* acc)
{
    if (trip <= 0) return;
    v2f xy = seg[0];
    for (int p = 0; p < trip; ++p) {
        const int pn = (p + 1 < trip) ? p + 1 : p;   // scalar select
        v2f nxt = seg[(size_t)pn * 64];              // depth-1 prefetch
        const v2f xx = (v2f){xy.x, xy.x};
        const v2f yy = (v2f){xy.y, xy.y};
        #pragma unroll
        for (int j = 0; j < NPAIR; ++j) {
            v2f dx  = xx + zxn[j];                              // v_pk_add
            v2f dy  = yy + zyn[j];                              // v_pk_add
            v2f m   = dy * dy;                                  // v_pk_mul
            v2f nd2 = __builtin_elementwise_fma(-dx, dx, -m);   // v_pk_fma
            v2f e   = (v2f){ fast_exp2(nd2.x), fast_exp2(nd2.y) };
            acc[j] += e;                                        // v_pk_add
        }
        xy = nxt;
    }
}

// ---------------------------------------------------------------------------
// Main — round-14 best (29.21us): 256-thread blocks (4 waves), TWO
// chunk-phases per wave (pair (p, 7-p): trips ~{30,17,17,17}), 8 blocks/CU
// co-resident, NT stores.
// ---------------------------------------------------------------------------
__global__ __launch_bounds__(256, 8) void diffusion_main_kernel(
    const float* __restrict__ z, const float* __restrict__ dconst,
    const v2f* __restrict__ table, const int* __restrict__ meta,
    float* __restrict__ out)
{
    __shared__ float tr[CPB * N_LABELS];   // 16 KB transpose buffer

    const int t = threadIdx.x;
    const int lane = t & 63, w = t >> 6;   // 4 waves

    // rotated pair assignment: wave handles chunks cA=p and cB=7-p
    const int p  = (w + (int)blockIdx.x) & 3;
    const int cA = p, cB = 7 - p;
    const int uA = cA * 64 + lane;
    const int uB = cB * 64 + lane;

    const int wbaseA = __builtin_amdgcn_readfirstlane(meta[uA]);
    const int tripA  = __builtin_amdgcn_readfirstlane(meta[NTHREADS + uA]);
    const int labA   = meta[2 * NTHREADS + uA];
    const float cntA = (float)meta[3 * NTHREADS + uA];
    const int wbaseB = __builtin_amdgcn_readfirstlane(meta[uB]);
    const int tripB  = __builtin_amdgcn_readfirstlane(meta[NTHREADS + uB]);
    const int labB   = meta[2 * NTHREADS + uB];
    const float cntB = (float)meta[3 * NTHREADS + uB];

    const float D    = dconst[0];
    const float sc   = sqrtf(HALF_LOG2E / D);
    const float norm = 1.0f / (6.28318530717958647f * D);
    const float baseA = cntA * 1e-12f;     // hoisted UNDERFLOW_NU
    const float baseB = cntB * 1e-12f;

    const int cell0 = blockIdx.x * CPB;
    v2f zxn[NPAIR], zyn[NPAIR], accA[NPAIR], accB[NPAIR];
    #pragma unroll
    for (int j = 0; j < NPAIR; ++j) {
        zxn[j] = (v2f){ -z[2 * (cell0 + 2 * j)]     * sc,
                        -z[2 * (cell0 + 2 * j + 1)] * sc };
        zyn[j] = (v2f){ -z[2 * (cell0 + 2 * j) + 1]     * sc,
                        -z[2 * (cell0 + 2 * j + 1) + 1] * sc };
        accA[j] = (v2f){0.f, 0.f};
        accB[j] = (v2f){0.f, 0.f};
    }

    kphase(table + wbaseA + lane, tripA, zxn, zyn, accA);
    kphase(table + wbaseB + lane, tripB, zxn, zyn, accB);

    // transpose in LDS so global stores are coalesced
    #pragma unroll
    for (int j = 0; j < NPAIR; ++j) {
        tr[(2 * j)     * N_LABELS + labA] = fmaf(accA[j].x, norm, baseA);
        tr[(2 * j + 1) * N_LABELS + labA] = fmaf(accA[j].y, norm, baseA);
        tr[(2 * j)     * N_LABELS + labB] = fmaf(accB[j].x, norm, baseB);
        tr[(2 * j + 1) * N_LABELS + labB] = fmaf(accB[j].y, norm, baseB);
    }
    __syncthreads();

    const v4f* tr4 = (const v4f*)tr;
    v4f* out4 = (v4f*)(out + (size_t)cell0 * N_LABELS);
    #pragma unroll
    for (int rr = 0; rr < CPB * N_LABELS / 4 / MTHREADS; ++rr)   // 4 iters
        __builtin_nontemporal_store(tr4[t + rr * MTHREADS],
                                    &out4[t + rr * MTHREADS]);
}

// ---------------------------------------------------------------------------
extern "C" void kernel_launch(void* const* d_in, const int* in_sizes, int n_in,
                              void* d_out, int out_size, void* d_ws, size_t ws_size,
                              hipStream_t stream)
{
    const float* z      = (const float*)d_in[0];  // (16384, 2)
    const float* dconst = (const float*)d_in[1];  // scalar
    const float* ex     = (const float*)d_in[2];  // (4096,)
    const float* ey     = (const float*)d_in[3];  // (4096,)
    const int*   labels = (const int*)d_in[4];    // (4096,)
    float*       out    = (float*)d_out;          // (16384, 512)

    float2* table = (float2*)d_ws;                                        // 48 KB
    int*    meta  = (int*)((char*)d_ws + (size_t)TABLE * sizeof(float2)); // 8 KB

    build_kernel<<<NBUILD, NTHREADS, 0, stream>>>(ex, ey, labels, dconst, table, meta);

    diffusion_main_kernel<<<N_CELLS / CPB, MTHREADS, 0, stream>>>(
        z, dconst, (const v2f*)table, meta, out);
}